// Round 2
// baseline (70.836 us; speedup 1.0000x reference)
//
#include <hip/hip_runtime.h>

// AdderVDSR collapses analytically:
//   adder_conv(h, w) = -sum|patch - w| < 0 everywhere (weights nonzero),
//   relu(negative) == 0 exactly  =>  h after the 16-block scan is identically 0.
//   out = conv3(0, out_w, out_b) + residual = out_b[c] + pixel_shuffle(conv3(x, up_w, up_b), 2)
// So we only compute the upsampler conv (3->12 ch, 3x3, pad 1), pixel-shuffle r=2,
// and add up_b + out_b.
//
// Round-1 bug: LDS weight staging used `if (t < 324)` with a 256-thread block,
// leaving sw[256..323] uninitialized (oc 9..11 garbage -> absmax 11.4).
// Fixed with a strided fill loop.

#define BATCH 2
#define CIN   3
#define HS    128
#define WS    128
#define H2    256
#define W2    256
#define OCHN  12   // 4*CIN
#define NW    (OCHN * CIN * 9)          // 324 weights
#define TOTAL (BATCH * CIN * H2 * W2)   // 393216

__global__ __launch_bounds__(256) void upshuffle_bias_kernel(
    const float* __restrict__ x,      // [2,3,128,128]
    const float* __restrict__ up_w,   // [12,3,3,3]
    const float* __restrict__ up_b,   // [12]
    const float* __restrict__ out_b,  // [3]
    float* __restrict__ out)          // [2,3,256,256]
{
    __shared__ float sw[NW];       // conv weights
    __shared__ float sbias[OCHN];  // up_b
    __shared__ float sob[CIN];     // out_b

    const int t = threadIdx.x;
    for (int i = t; i < NW; i += 256) sw[i] = up_w[i];   // 324 > 256: must stride!
    if (t < OCHN) sbias[t] = up_b[t];
    if (t < CIN)  sob[t]   = out_b[t];
    __syncthreads();

    const int idx = blockIdx.x * 256 + t;
    if (idx >= TOTAL) return;

    // out layout [b, c, y2, x2] with W2=256, H2=256
    const int x2  = idx & (W2 - 1);
    const int y2  = (idx >> 8) & (H2 - 1);
    const int rem = idx >> 16;          // 0..5
    const int c   = rem % CIN;
    const int b   = rem / CIN;

    // invert pixel shuffle: out[b,c,2h+r1,2w+r2] = y[b, c*4 + r1*2 + r2, h, w]
    const int h  = y2 >> 1;
    const int w  = x2 >> 1;
    const int oc = c * 4 + (y2 & 1) * 2 + (x2 & 1);

    float sum = sbias[oc];

    #pragma unroll
    for (int ic = 0; ic < CIN; ++ic) {
        const float* __restrict__ xp = x + ((b * CIN + ic) * HS) * WS;
        const float* __restrict__ wp = sw + (oc * CIN + ic) * 9;
        #pragma unroll
        for (int ky = 0; ky < 3; ++ky) {
            const int iy = h + ky - 1;
            const bool yok = (iy >= 0) && (iy < HS);
            #pragma unroll
            for (int kx = 0; kx < 3; ++kx) {
                const int ix = w + kx - 1;
                const bool ok = yok && (ix >= 0) && (ix < WS);
                const float xv = ok ? xp[iy * WS + ix] : 0.0f;
                sum = fmaf(xv, wp[ky * 3 + kx], sum);
            }
        }
    }

    out[idx] = sum + sob[c];
}

extern "C" void kernel_launch(void* const* d_in, const int* in_sizes, int n_in,
                              void* d_out, int out_size, void* d_ws, size_t ws_size,
                              hipStream_t stream) {
    // setup_inputs order: x, up_w, up_b, in_w, in_b, adder_w, out_w, out_b
    const float* x     = (const float*)d_in[0];
    const float* up_w  = (const float*)d_in[1];
    const float* up_b  = (const float*)d_in[2];
    const float* out_b = (const float*)d_in[7];
    float* out = (float*)d_out;

    const int blocks = (TOTAL + 255) / 256;  // 1536
    upshuffle_bias_kernel<<<blocks, 256, 0, stream>>>(x, up_w, up_b, out_b, out);
}

// Round 3
// 69.859 us; speedup vs baseline: 1.0140x; 1.0140x over previous
//
#include <hip/hip_runtime.h>

// AdderVDSR collapses analytically:
//   adder_conv(h, w) = -sum|patch - w| < 0 everywhere (nonzero weights),
//   relu(negative) == 0 exactly  =>  h after the 16-block scan is identically 0.
//   out = conv3(0, out_w, out_b) + residual
//       = out_b[c] + pixel_shuffle(conv3(x, up_w, up_b), 2)
// Only the upsampler conv (3->12ch, 3x3, pad 1) + shuffle + biases remain.
//
// R3 structure: one thread per SOURCE pixel (b,c,h,w). The 2x2 output cell
// (4 output channels oc = c*4 + r1*2 + r2) shares one 27-element patch:
// 4x fewer global loads than one-thread-per-output. (b,c) is block-uniform,
// so weights/biases are uniform LDS broadcasts. Stores: 2x float2, coalesced.

#define BATCH 2
#define CIN   3
#define HS    128
#define WS    128
#define H2    256
#define W2    256

__global__ __launch_bounds__(256) void upshuffle4_kernel(
    const float* __restrict__ x,      // [2,3,128,128]
    const float* __restrict__ up_w,   // [12,3,3,3] = [c][oc4][ic][ky][kx] w/ oc=c*4+oc4
    const float* __restrict__ up_b,   // [12]
    const float* __restrict__ out_b,  // [3]
    float* __restrict__ out)          // [2,3,256,256]
{
    __shared__ float sw[4 * CIN * 9]; // 108 weights for this block's c group
    __shared__ float sb4[4];          // up_b for the 4 ocs
    __shared__ float sob;             // out_b[c]

    const int blocksPerPlane = (HS * WS) / 256;        // 64
    const int bc = blockIdx.x / blocksPerPlane;        // 0..5, block-uniform
    const int c  = bc % CIN;
    const int b  = bc / CIN;

    const int t = threadIdx.x;
    if (t < 108) sw[t]  = up_w[c * 108 + t];           // [oc4][ic][3][3]
    if (t < 4)   sb4[t] = up_b[c * 4 + t];
    if (t == 0)  sob    = out_b[c];
    __syncthreads();

    const int pix = (blockIdx.x % blocksPerPlane) * 256 + t;  // 0..16383
    const int w   = pix & (WS - 1);
    const int h   = pix >> 7;                          // WS == 128

    const float* __restrict__ xb = x + (size_t)(b * CIN) * HS * WS;

    // acc[r1*2+r2] for out[b,c,2h+r1,2w+r2]
    float a00 = sb4[0], a01 = sb4[1], a10 = sb4[2], a11 = sb4[3];

    #pragma unroll
    for (int ic = 0; ic < CIN; ++ic) {
        const float* __restrict__ xp = xb + ic * HS * WS;
        #pragma unroll
        for (int ky = 0; ky < 3; ++ky) {
            const int iy   = h + ky - 1;
            const bool yok = (unsigned)iy < (unsigned)HS;
            const float* __restrict__ row = xp + iy * WS + w;
            const float p0 = (yok && w > 0)      ? row[-1] : 0.0f;
            const float p1 =  yok                ? row[0]  : 0.0f;
            const float p2 = (yok && w < WS - 1) ? row[1]  : 0.0f;
            const float* __restrict__ wp = sw + ic * 9 + ky * 3;  // + oc4*27
            a00 = fmaf(p0, wp[0],      fmaf(p1, wp[1],      fmaf(p2, wp[2],      a00)));
            a01 = fmaf(p0, wp[27],     fmaf(p1, wp[28],     fmaf(p2, wp[29],     a01)));
            a10 = fmaf(p0, wp[54],     fmaf(p1, wp[55],     fmaf(p2, wp[56],     a10)));
            a11 = fmaf(p0, wp[81],     fmaf(p1, wp[82],     fmaf(p2, wp[83],     a11)));
        }
    }

    float2 r0 = make_float2(a00 + sob, a01 + sob);
    float2 r1 = make_float2(a10 + sob, a11 + sob);
    float* __restrict__ ob = out + (((size_t)(b * CIN + c) * H2) + 2 * h) * W2 + 2 * w;
    *(float2*)ob        = r0;
    *(float2*)(ob + W2) = r1;
}

extern "C" void kernel_launch(void* const* d_in, const int* in_sizes, int n_in,
                              void* d_out, int out_size, void* d_ws, size_t ws_size,
                              hipStream_t stream) {
    // setup_inputs order: x, up_w, up_b, in_w, in_b, adder_w, out_w, out_b
    const float* x     = (const float*)d_in[0];
    const float* up_w  = (const float*)d_in[1];
    const float* up_b  = (const float*)d_in[2];
    const float* out_b = (const float*)d_in[7];
    float* out = (float*)d_out;

    const int blocks = BATCH * CIN * (HS * WS) / 256;  // 384
    upshuffle4_kernel<<<blocks, 256, 0, stream>>>(x, up_w, up_b, out_b, out);
}